// Round 17
// baseline (126.042 us; speedup 1.0000x reference)
//
#include <hip/hip_runtime.h>

// Problem constants
#define K_CODES 512
#define DIM 80
#define SEQ 4096
#define NVEC 131072
#define NELEM ((size_t)NVEC * DIM)
#define VPB 64                       // vectors per block: 2 waves x 2 sets x 16
#define NTILES 32                    // 16-code tiles
#define TILE_BYTES 6144              // 384 short8 per tile

typedef short short8 __attribute__((ext_vector_type(8)));
typedef float f32x4 __attribute__((ext_vector_type(4)));

// ws layout: ghist[512] @0 | gsq @2048 | wsq[512] @4096 | wfrag @8192 (196608 B)
#define WS_GSQ   2048
#define WS_WSQ   4096
#define WS_WFRAG 8192

__device__ __forceinline__ unsigned short f2bf(float f) {
    union { float f; unsigned int u; } c; c.f = f;
    unsigned int r = c.u + 0x7FFFu + ((c.u >> 16) & 1u);   // RNE
    return (unsigned short)(r >> 16);
}
__device__ __forceinline__ float bf2f(unsigned short h) {
    union { float f; unsigned int u; } c; c.u = ((unsigned int)h) << 16;
    return c.f;
}

__device__ __forceinline__ void gload_lds16(const void* g, void* l) {
    __builtin_amdgcn_global_load_lds(
        (const __attribute__((address_space(1))) void*)g,
        (__attribute__((address_space(3))) void*)l, 16, 0, 0);
}

// Fused setup: wfrag (fragment-ordered split codebook) + wsq (row norms).
// wfrag: [t16 0..31][g 0..5][lane 0..63] short8; g<3: hi,ks=g; g>=3: lo,ks=g-3;
//        lane=(cg<<4)|cl; value = w{hi,lo}[code=t16*16+cl][c=ks*32+cg*8 ..+8)
__global__ void vq_setup(const float* __restrict__ weight,
                         short8* __restrict__ wf, float* __restrict__ wsq)
{
    int idx = blockIdx.x * 256 + threadIdx.x;   // 48 blocks -> 12288
    if (blockIdx.x < 2) {
        int k = blockIdx.x * 256 + threadIdx.x;
        const float* w = weight + (size_t)k * DIM;
        float s = 0.f;
#pragma unroll
        for (int c = 0; c < DIM; ++c) s = fmaf(w[c], w[c], s);
        wsq[k] = s;
    }
    int t   = idx / 384;
    int rem = idx - t * 384;
    int g   = rem >> 6, l = rem & 63;
    int cl  = l & 15, cg = l >> 4;
    int ks  = g % 3, h = g / 3;
    int code = t * 16 + cl;
    int c0 = ks * 32 + cg * 8;
    short8 v;
#pragma unroll
    for (int j = 0; j < 8; ++j) {
        int c = c0 + j;
        unsigned short r = 0;
        if (c < DIM) {
            float f = weight[(size_t)code * DIM + c];
            unsigned short hb = f2bf(f);
            r = h ? f2bf(f - bf2f(hb)) : hb;
        }
        v[j] = (short)r;
    }
    wf[idx] = v;
}

// Fused distance GEMM + argmin + output. R16's verified K-loop (2 A-sets,
// 6 B-frags, 6 accs, stage-early/barrier-late) at 2 waves/block (2048 blocks
// -> 8 barrier-groups/CU). Tail: every lane learns its own vector's winning
// code via one cross-group shfl, then emits quantized output (exact fp32
// codebook gather, 64B-coalesced stores), loss (from in-register x ~ hi+lo,
// error ~2^-18), and histogram -- no separate epilogue kernel, no x re-read.
__global__ __launch_bounds__(128, 4) void vq_argmin(
    const float* __restrict__ x, const short8* __restrict__ wf,
    const float* __restrict__ wsq, const float* __restrict__ weight,
    float* __restrict__ out, float* __restrict__ gsq, int* __restrict__ ghist)
{
    __shared__ short8 bbuf[2][384];    // 2 x 6 KB, fragment-ordered B tiles
    __shared__ float wsq_lds[K_CODES]; // 2 KB
    __shared__ int lhist[K_CODES];     // 2 KB
    __shared__ float lsum[2];

    const int tid = threadIdx.x;
    *(float4*)&wsq_lds[tid * 4] = *(const float4*)&wsq[tid * 4];
    for (int i = tid; i < K_CODES; i += 128) lhist[i] = 0;

    const int v0 = blockIdx.x * VPB;
    const int b  = v0 >> 12;
    const int l0 = v0 & 4095;
    const float* xbase = x + (size_t)b * DIM * SEQ + l0;

    const int lane = tid & 63, wid = tid >> 6;
    const int cg = lane >> 4;          // k-group 0..3
    const int cl = lane & 15;          // A row / B col
    const int ar0 = wid * 32 + cl;     // set-0 local vector
    const int ar1 = ar0 + 16;          // set-1

    // ---- stage tile 0 (linear copy: 3 x 16B per thread) ----
    {
        const char* src = (const char*)wf + tid * 16;
        char* dst = (char*)&bbuf[0][0] + tid * 16;
        gload_lds16(src, dst);
        gload_lds16(src + 2048, dst + 2048);
        gload_lds16(src + 4096, dst + 4096);
    }

    // ---- A fragments (2 sets, hi/lo), direct from global ----
    short8 ahi0[3], alo0[3], ahi1[3], alo1[3];
#pragma unroll
    for (int ks = 0; ks < 3; ++ks) {
#pragma unroll
        for (int j = 0; j < 8; ++j) {
            int c = ks * 32 + cg * 8 + j;
            unsigned short h0 = 0, p0 = 0, h1 = 0, p1 = 0;
            if (c < DIM) {
                float f0 = xbase[(size_t)c * SEQ + ar0];
                float f1 = xbase[(size_t)c * SEQ + ar1];
                h0 = f2bf(f0); p0 = f2bf(f0 - bf2f(h0));
                h1 = f2bf(f1); p1 = f2bf(f1 - bf2f(h1));
            }
            ahi0[ks][j] = (short)h0; alo0[ks][j] = (short)p0;
            ahi1[ks][j] = (short)h1; alo1[ks][j] = (short)p1;
        }
    }

    float bestd[2][4];
    int   bestk[2][4];
#pragma unroll
    for (int s = 0; s < 2; ++s)
#pragma unroll
        for (int r = 0; r < 4; ++r) { bestd[s][r] = 3.4028235e38f; bestk[s][r] = 0; }

    __syncthreads();   // stage(0) drained; wsq_lds + lhist visible

    for (int t = 0; t < NTILES; ++t) {
        // stage(t+1) FIRST -- overlaps the compute phase, drained at phase-end
        // barrier. Target buffer's readers (phase t-1) finished at prev barrier.
        if (t + 1 < NTILES) {
            const char* src = (const char*)wf + (size_t)(t + 1) * TILE_BYTES + tid * 16;
            char* dst = (char*)&bbuf[(t + 1) & 1][0] + tid * 16;
            gload_lds16(src, dst);
            gload_lds16(src + 2048, dst + 2048);
            gload_lds16(src + 4096, dst + 4096);
        }

        const short8* bb = bbuf[t & 1];
        short8 bh0 = bb[lane];
        short8 bh1 = bb[64 + lane];
        short8 bh2 = bb[128 + lane];
        short8 bl0 = bb[192 + lane];
        short8 bl1 = bb[256 + lane];
        short8 bl2 = bb[320 + lane];
        float wv = wsq_lds[t * 16 + cl];

        f32x4 a00 = {0.f,0.f,0.f,0.f}, a01 = {0.f,0.f,0.f,0.f}, a02 = {0.f,0.f,0.f,0.f};
        f32x4 a10 = {0.f,0.f,0.f,0.f}, a11 = {0.f,0.f,0.f,0.f}, a12 = {0.f,0.f,0.f,0.f};
        __builtin_amdgcn_s_setprio(1);
        // R16-identical sequence: per set 3 chains (hh -> hl -> lh), sets interleaved
        a00 = __builtin_amdgcn_mfma_f32_16x16x32_bf16(ahi0[0], bh0, a00, 0, 0, 0);
        a01 = __builtin_amdgcn_mfma_f32_16x16x32_bf16(ahi0[1], bh1, a01, 0, 0, 0);
        a02 = __builtin_amdgcn_mfma_f32_16x16x32_bf16(ahi0[2], bh2, a02, 0, 0, 0);
        a10 = __builtin_amdgcn_mfma_f32_16x16x32_bf16(ahi1[0], bh0, a10, 0, 0, 0);
        a11 = __builtin_amdgcn_mfma_f32_16x16x32_bf16(ahi1[1], bh1, a11, 0, 0, 0);
        a12 = __builtin_amdgcn_mfma_f32_16x16x32_bf16(ahi1[2], bh2, a12, 0, 0, 0);
        a00 = __builtin_amdgcn_mfma_f32_16x16x32_bf16(ahi0[0], bl0, a00, 0, 0, 0);
        a01 = __builtin_amdgcn_mfma_f32_16x16x32_bf16(ahi0[1], bl1, a01, 0, 0, 0);
        a02 = __builtin_amdgcn_mfma_f32_16x16x32_bf16(ahi0[2], bl2, a02, 0, 0, 0);
        a10 = __builtin_amdgcn_mfma_f32_16x16x32_bf16(ahi1[0], bl0, a10, 0, 0, 0);
        a11 = __builtin_amdgcn_mfma_f32_16x16x32_bf16(ahi1[1], bl1, a11, 0, 0, 0);
        a12 = __builtin_amdgcn_mfma_f32_16x16x32_bf16(ahi1[2], bl2, a12, 0, 0, 0);
        a00 = __builtin_amdgcn_mfma_f32_16x16x32_bf16(alo0[0], bh0, a00, 0, 0, 0);
        a01 = __builtin_amdgcn_mfma_f32_16x16x32_bf16(alo0[1], bh1, a01, 0, 0, 0);
        a02 = __builtin_amdgcn_mfma_f32_16x16x32_bf16(alo0[2], bh2, a02, 0, 0, 0);
        a10 = __builtin_amdgcn_mfma_f32_16x16x32_bf16(alo1[0], bh0, a10, 0, 0, 0);
        a11 = __builtin_amdgcn_mfma_f32_16x16x32_bf16(alo1[1], bh1, a11, 0, 0, 0);
        a12 = __builtin_amdgcn_mfma_f32_16x16x32_bf16(alo1[2], bh2, a12, 0, 0, 0);
        __builtin_amdgcn_s_setprio(0);

        const int code = t * 16 + cl;
#pragma unroll
        for (int r = 0; r < 4; ++r) {
            float d0 = a00[r] + a01[r] + a02[r];
            float q0 = fmaf(-2.f, d0, wv);
            if (q0 < bestd[0][r]) { bestd[0][r] = q0; bestk[0][r] = code; }
            float d1 = a10[r] + a11[r] + a12[r];
            float q1 = fmaf(-2.f, d1, wv);
            if (q1 < bestd[1][r]) { bestd[1][r] = q1; bestk[1][r] = code; }
        }

        __syncthreads();   // drains stage(t+1); all reads of bbuf[t&1] done
    }

    // ---- cross-lane argmin (lexicographic); all 16 lanes get the result ----
#pragma unroll
    for (int s = 0; s < 2; ++s) {
#pragma unroll
        for (int r = 0; r < 4; ++r) {
            float d = bestd[s][r]; int k = bestk[s][r];
#pragma unroll
            for (int off = 1; off < 16; off <<= 1) {
                float od = __shfl_xor(d, off, 64);
                int   ok = __shfl_xor(k, off, 64);
                if (od < d || (od == d && ok < k)) { d = od; k = ok; }
            }
            bestk[s][r] = k;   // valid in every lane of the 16-lane group
        }
    }

    // ---- fused epilogue: each lane outputs its OWN vector (local id cl) ----
    // k for vector (s*16 + cl) lives in lane ((cl>>2)<<4)|(cl&3) as bestk[s][cl&3].
    float sq = 0.f;
    const int r3 = cl & 3;
    const int srcl = ((cl >> 2) << 4) | r3;
#pragma unroll
    for (int s = 0; s < 2; ++s) {
        int kr = bestk[s][0];
        kr = (r3 == 1) ? bestk[s][1] : kr;
        kr = (r3 == 2) ? bestk[s][2] : kr;
        kr = (r3 == 3) ? bestk[s][3] : kr;
        const int kv = __shfl(kr, srcl, 64);
        if (cg == 0) atomicAdd(&lhist[kv], 1);

        const float* wr = weight + (size_t)kv * DIM;
        const int av = wid * 32 + s * 16 + cl;             // local vector id
        float* op = out + 1 + (size_t)b * DIM * SEQ + l0 + av;

#pragma unroll
        for (int ks = 0; ks < 3; ++ks) {
            const int c0 = ks * 32 + cg * 8;
            if (c0 < DIM) {                                 // ks=2 -> only cg<2
                float4 wa = *(const float4*)(wr + c0);
                float4 wb = *(const float4*)(wr + c0 + 4);
                float w0 = wa.x, w1 = wa.y, w2 = wa.z, w3 = wa.w;
                float w4 = wb.x, w5 = wb.y, w6 = wb.z, w7 = wb.w;
#define EMIT(J, WJ)                                                              \
                {                                                                \
                    unsigned short hb = (unsigned short)(s ? ahi1[ks][J] : ahi0[ks][J]); \
                    unsigned short pb = (unsigned short)(s ? alo1[ks][J] : alo0[ks][J]); \
                    float xr = bf2f(hb) + bf2f(pb);                              \
                    float e = WJ - xr;                                           \
                    sq = fmaf(e, e, sq);                                         \
                    op[(size_t)(c0 + J) * SEQ] = WJ;                             \
                }
                EMIT(0, w0) EMIT(1, w1) EMIT(2, w2) EMIT(3, w3)
                EMIT(4, w4) EMIT(5, w5) EMIT(6, w6) EMIT(7, w7)
#undef EMIT
            }
        }
    }

    // ---- loss reduction + histogram flush ----
#pragma unroll
    for (int off = 32; off; off >>= 1) sq += __shfl_down(sq, off, 64);
    if (lane == 0) lsum[wid] = sq;
    __syncthreads();
    if (tid == 0) atomicAdd(gsq, lsum[0] + lsum[1]);
    for (int i = tid; i < K_CODES; i += 128) {
        int cnt = lhist[i];
        if (cnt) atomicAdd(&ghist[i], cnt);
    }
}

__global__ void vq_finalize(const int* __restrict__ hist,
                            const float* __restrict__ gsq,
                            float* __restrict__ out, int out_last)
{
    __shared__ float part[8];
    int t = threadIdx.x;  // 512 threads
    float p = (float)hist[t] * (1.0f / (float)NVEC);
    float term = p * logf(p + 1e-10f);
#pragma unroll
    for (int off = 32; off; off >>= 1) term += __shfl_down(term, off, 64);
    if ((t & 63) == 0) part[t >> 6] = term;
    __syncthreads();
    if (t == 0) {
        float s = 0.f;
#pragma unroll
        for (int i = 0; i < 8; ++i) s += part[i];
        out[out_last] = expf(-s);
        out[0] = 1.25f * gsq[0] / (float)NELEM;
    }
}

extern "C" void kernel_launch(void* const* d_in, const int* in_sizes, int n_in,
                              void* d_out, int out_size, void* d_ws, size_t ws_size,
                              hipStream_t stream) {
    const float* x = (const float*)d_in[0];
    const float* weight = (const float*)d_in[1];
    float* out = (float*)d_out;

    int* ghist = (int*)d_ws;
    float* gsq = (float*)((char*)d_ws + WS_GSQ);
    float* wsq = (float*)((char*)d_ws + WS_WSQ);
    short8* wf = (short8*)((char*)d_ws + WS_WFRAG);

    hipMemsetAsync(d_ws, 0, 2052, stream);

    vq_setup<<<48, 256, 0, stream>>>(weight, wf, wsq);
    vq_argmin<<<NVEC / VPB, 128, 0, stream>>>(x, wf, wsq, weight, out, gsq, ghist);
    vq_finalize<<<1, K_CODES, 0, stream>>>(ghist, gsq, out, out_size - 1);
}